// Round 11
// baseline (428.593 us; speedup 1.0000x reference)
//
#include <hip/hip_runtime.h>
#include <math.h>

#define NN 16384
#define EE 262144

typedef __bf16 v8bf __attribute__((ext_vector_type(8)));
typedef __bf16 v4bf __attribute__((ext_vector_type(4)));
typedef float  v4f  __attribute__((ext_vector_type(4)));
typedef float  v2f  __attribute__((ext_vector_type(2)));

// ---- workspace layout (units of 4-byte elements) ----
#define OFF_CNT     0                         // 2*NN ints
#define OFF_FILL    (2*NN)                    // 2*NN ints
#define OFF_ROWPTR  (4*NN)                    // 2*(NN+1) ints
#define OFF_COLSRC  98816                     // 2*EE ints (byte offsets)
#define OFF_H       623104                    // 2*NN*64 f32
#define OFF_HN      (OFF_H  + 2*NN*64)        // 2*NN*64 f32
#define OFF_Q       (OFF_HN + 2*NN*64)        // 2*NN*256 bf16 (512B rows)
#define OFF_KV      (OFF_Q  + 2*NN*128)       // 2*NN rows of 768 B (K fp8 256B | V bf16 512B)
#define OFF_R       (OFF_KV + 2*NN*192)       // 2*NN*64 f32

#define LDA 72   // padded bf16 row stride

__device__ __forceinline__ float blo(unsigned u) { return __uint_as_float(u << 16); }
__device__ __forceinline__ float bhi(unsigned u) { return __uint_as_float(u & 0xffff0000u); }
__device__ __forceinline__ unsigned short f2b(float f) {
  __bf16 h = (__bf16)f;
  return *(unsigned short*)&h;
}

// ======================= CSR build =======================
__global__ void count_kernel(const int* __restrict__ ei, int* __restrict__ cnt) {
  int idx = blockIdx.x * 256 + threadIdx.x;
  if (idx >= 2 * EE) return;
  int et = idx >> 18;
  int j  = idx & (EE - 1);
  int dst = ei[et * 2 * EE + EE + j];
  atomicAdd(&cnt[et * NN + dst], 1);
}

__global__ __launch_bounds__(1024) void scan_kernel(const int* __restrict__ cnt,
                                                    int* __restrict__ rowptr,
                                                    int* __restrict__ fill) {
  int et = blockIdx.x;
  const int* c = cnt + et * NN;
  __shared__ int sums[1024];
  int tid = threadIdx.x;
  int base = tid * 16;
  int loc[16];
  int s = 0;
#pragma unroll
  for (int i = 0; i < 16; ++i) { loc[i] = s; s += c[base + i]; }
  sums[tid] = s;
  __syncthreads();
  for (int off = 1; off < 1024; off <<= 1) {
    int v = 0;
    if (tid >= off) v = sums[tid - off];
    __syncthreads();
    if (tid >= off) sums[tid] += v;
    __syncthreads();
  }
  int ebase = (tid == 0) ? 0 : sums[tid - 1];
  int* rp = rowptr + et * (NN + 1);
  int* fl = fill + et * NN;
#pragma unroll
  for (int i = 0; i < 16; ++i) {
    rp[base + i] = ebase + loc[i];
    fl[base + i] = ebase + loc[i];
  }
  if (tid == 1023) rp[NN] = sums[1023];
}

// colsrc holds BYTE offset of the src node's KV row: (et*NN + src) * 768
__global__ void scatter_kernel(const int* __restrict__ ei, int* __restrict__ fill,
                               int* __restrict__ colsrc) {
  int idx = blockIdx.x * 256 + threadIdx.x;
  if (idx >= 2 * EE) return;
  int et = idx >> 18;
  int j  = idx & (EE - 1);
  int src = ei[et * 2 * EE + j];
  int dst = ei[et * 2 * EE + EE + j];
  int pos = atomicAdd(&fill[et * NN + dst], 1);
  colsrc[et * EE + pos] = (et * NN + src) * 768;
}

// ======================= shared projection-from-LDS machinery =======================
// hA: 64 rows (bf16, stride LDA) resident in LDS; project through up to 4
// weight mats (f32 [64][Ncols]) into outputs. otype 0=f32 1=bf16 2=fp8.
struct ProjDesc { const float *B, *bias; char* C; int Ncols, Cld, otype; };

__device__ __forceinline__ void project_from_lds(const __bf16* hA, __bf16* Bs,
                                                 const ProjDesc* pd, int nd,
                                                 int row0, int tid) {
  const int w = tid >> 6, lane = tid & 63;
  const int l16 = lane & 15, quad = lane >> 4;
  for (int di = 0; di < nd; ++di) {
    ProjDesc g = pd[di];
    for (int ct0 = 0; ct0 < (g.Ncols >> 6); ++ct0) {
      const int col0 = ct0 * 64;
      __syncthreads();   // prior MFMA done reading Bs / hA writes visible
#pragma unroll
      for (int it = 0; it < 4; ++it) {
        int fi = it * 256 + tid;
        int kk = fi >> 4;
        int nq = (fi & 15) << 2;
        float4 b = *(const float4*)(g.B + (size_t)kk * g.Ncols + col0 + nq);
        Bs[(nq + 0) * LDA + kk] = (__bf16)b.x;
        Bs[(nq + 1) * LDA + kk] = (__bf16)b.y;
        Bs[(nq + 2) * LDA + kk] = (__bf16)b.z;
        Bs[(nq + 3) * LDA + kk] = (__bf16)b.w;
      }
      __syncthreads();

      v4f acc[4];
#pragma unroll
      for (int ct = 0; ct < 4; ++ct)
#pragma unroll
        for (int r = 0; r < 4; ++r) acc[ct][r] = 0.f;
#pragma unroll
      for (int ks = 0; ks < 2; ++ks) {
        v8bf a = *(v8bf*)&hA[(w * 16 + l16) * LDA + ks * 32 + quad * 8];
#pragma unroll
        for (int ct = 0; ct < 4; ++ct) {
          v8bf bb = *(v8bf*)&Bs[(ct * 16 + l16) * LDA + ks * 32 + quad * 8];
          acc[ct] = __builtin_amdgcn_mfma_f32_16x16x32_bf16(a, bb, acc[ct], 0, 0, 0);
        }
      }
#pragma unroll
      for (int ct = 0; ct < 4; ++ct) {
        int col = col0 + ct * 16 + l16;
        float bv = g.bias[col];
#pragma unroll
        for (int r = 0; r < 4; ++r) {
          size_t row = row0 + w * 16 + quad * 4 + r;
          char* cp = g.C + row * (size_t)g.Cld;
          float v = acc[ct][r] + bv;
          if (g.otype == 0)      *(float*)(cp + col * 4) = v;
          else if (g.otype == 1) *(unsigned short*)(cp + col * 2) = f2b(v);
          else {
            unsigned pk = __builtin_amdgcn_cvt_pk_fp8_f32(v, v, 0, false);
            *(unsigned char*)(cp + col) = (unsigned char)(pk & 0xff);
          }
        }
      }
    }
  }
}

// ======================= fused input-proj + layer-0 qkv/skip =======================
struct InQkvPack {
  const float *x, *Win, *bin, *temb, *pos;
  const float *Wq, *bq, *Wk, *bk, *Wv, *bv, *Ws, *bs;   // layer-0 bases
  float* H;
  unsigned short* Qb;    // bf16 rows, 512B stride
  char* KVb;             // 768B rows
  float* Rb;
};

__global__ __launch_bounds__(256) void in_qkv(InQkvPack p) {
  const int t = blockIdx.y;
  const int row0 = blockIdx.x * 64;
  const int tid = threadIdx.x;
  const int w = tid >> 6, lane = tid & 63;
  const int l16 = lane & 15, quad = lane >> 4;

  __shared__ __bf16 As[64 * LDA];
  __shared__ __bf16 Bs[64 * LDA];

  const float* xs = p.x + ((size_t)t * NN) * 64;
  const float* Win = p.Win + (size_t)t * 64 * 64;

  // stage x rows and W_in tile
#pragma unroll
  for (int it = 0; it < 4; ++it) {
    int fi = it * 256 + tid;
    int grow = fi >> 4;
    int kq = (fi & 15) << 2;
    float4 a = *(const float4*)(xs + (size_t)(row0 + grow) * 64 + kq);
    v4bf c = { (__bf16)a.x, (__bf16)a.y, (__bf16)a.z, (__bf16)a.w };
    *(v4bf*)&As[grow * LDA + kq] = c;
    // W_in tile (transposed)
    int kk = grow, nq = kq;
    float4 b = *(const float4*)(Win + (size_t)kk * 64 + nq);
    Bs[(nq + 0) * LDA + kk] = (__bf16)b.x;
    Bs[(nq + 1) * LDA + kk] = (__bf16)b.y;
    Bs[(nq + 2) * LDA + kk] = (__bf16)b.z;
    Bs[(nq + 3) * LDA + kk] = (__bf16)b.w;
  }
  __syncthreads();

  v4f acc[4];
#pragma unroll
  for (int ct = 0; ct < 4; ++ct)
#pragma unroll
    for (int r = 0; r < 4; ++r) acc[ct][r] = 0.f;
#pragma unroll
  for (int ks = 0; ks < 2; ++ks) {
    v8bf a = *(v8bf*)&As[(w * 16 + l16) * LDA + ks * 32 + quad * 8];
#pragma unroll
    for (int ct = 0; ct < 4; ++ct) {
      v8bf bb = *(v8bf*)&Bs[(ct * 16 + l16) * LDA + ks * 32 + quad * 8];
      acc[ct] = __builtin_amdgcn_mfma_f32_16x16x32_bf16(a, bb, acc[ct], 0, 0, 0);
    }
  }

  // epilogue: h = acc + b_in + type_emb + pos ; write H (f32) and As (bf16)
  const float* bin = p.bin + t * 64;
  const float* temb = p.temb + t * 64;
  const float* pos = p.pos + ((size_t)t * NN) * 64;
#pragma unroll
  for (int ct = 0; ct < 4; ++ct) {
    int col = ct * 16 + l16;
    float bb = bin[col] + temb[col];
#pragma unroll
    for (int r = 0; r < 4; ++r) {
      int lrow = w * 16 + quad * 4 + r;
      size_t row = (size_t)t * NN + row0 + lrow;
      float v = acc[ct][r] + bb + pos[(size_t)(row0 + lrow) * 64 + col];
      p.H[row * 64 + col] = v;
      As[lrow * LDA + col] = (__bf16)v;
    }
  }

  // layer-0 projections from h
  int tq = 1 - t;   // edge type for which t is dst
  ProjDesc pd[4];
  pd[0] = { p.Wq + (size_t)tq * 64 * 256, p.bq + tq * 256,
            (char*)p.Qb + (size_t)t * NN * 512, 256, 512, 1 };
  pd[1] = { p.Wk + (size_t)t * 64 * 256, p.bk + t * 256,
            p.KVb + (size_t)t * NN * 768, 256, 768, 2 };
  pd[2] = { p.Wv + (size_t)t * 64 * 256, p.bv + t * 256,
            p.KVb + (size_t)t * NN * 768 + 256, 256, 768, 1 };
  pd[3] = { p.Ws + (size_t)tq * 64 * 64, p.bs + tq * 64,
            (char*)(p.Rb + (size_t)t * NN * 64), 64, 256, 0 };
  project_from_lds(As, Bs, pd, 4, row0, tid);
}

// ======================= fused FF + (next-layer qkv | out-proj) =======================
struct FFPack {
  const float *HN, *W1, *b1, *W2, *b2;
  float* H;
  // mode 1: next-layer qkv (bases for layer l+1)
  const float *Wq, *bq, *Wk, *bk, *Wv, *bv, *Ws, *bs;
  unsigned short* Qb; char* KVb; float* Rb;
  // mode 2: out-proj
  const float *Wout, *bout;
  float* outbuf;
  int mode;   // 1 = qkv-next, 2 = out-proj
};

__global__ __launch_bounds__(256) void ff_fused(FFPack p) {
  const int t = blockIdx.y;
  const int row0 = blockIdx.x * 64;
  const int tid = threadIdx.x;
  const int w = tid >> 6, lane = tid & 63;
  const int l16 = lane & 15, quad = lane >> 4;

  const float* A  = p.HN + ((size_t)t * NN) * 64;
  const float* W1 = p.W1 + (size_t)t * 64 * 256;
  const float* b1 = p.b1 + t * 256;
  const float* W2 = p.W2 + (size_t)t * 256 * 64;
  const float* b2 = p.b2 + t * 64;

  __shared__ __bf16 As[64 * LDA];
  __shared__ __bf16 A2[64 * LDA];
  __shared__ __bf16 B1s[64 * LDA];
  __shared__ __bf16 B2s[64 * LDA];

#pragma unroll
  for (int it = 0; it < 4; ++it) {
    int fi = it * 256 + tid;
    int grow = fi >> 4;
    int kq = (fi & 15) << 2;
    float4 a = *(const float4*)(A + (size_t)(row0 + grow) * 64 + kq);
    v4bf c = { (__bf16)a.x, (__bf16)a.y, (__bf16)a.z, (__bf16)a.w };
    *(v4bf*)&As[grow * LDA + kq] = c;
  }

  v4f acc2[4];
#pragma unroll
  for (int ct = 0; ct < 4; ++ct)
#pragma unroll
    for (int r = 0; r < 4; ++r) acc2[ct][r] = 0.f;

  for (int c1 = 0; c1 < 4; ++c1) {
#pragma unroll
    for (int it = 0; it < 4; ++it) {
      int fi = it * 256 + tid;
      int kk = fi >> 4;
      int nq = (fi & 15) << 2;
      float4 b = *(const float4*)(W1 + (size_t)kk * 256 + c1 * 64 + nq);
      B1s[(nq + 0) * LDA + kk] = (__bf16)b.x;
      B1s[(nq + 1) * LDA + kk] = (__bf16)b.y;
      B1s[(nq + 2) * LDA + kk] = (__bf16)b.z;
      B1s[(nq + 3) * LDA + kk] = (__bf16)b.w;
      float4 b2v = *(const float4*)(W2 + (size_t)(c1 * 64 + kk) * 64 + nq);
      B2s[(nq + 0) * LDA + kk] = (__bf16)b2v.x;
      B2s[(nq + 1) * LDA + kk] = (__bf16)b2v.y;
      B2s[(nq + 2) * LDA + kk] = (__bf16)b2v.z;
      B2s[(nq + 3) * LDA + kk] = (__bf16)b2v.w;
    }
    __syncthreads();

    v4f acc1[4];
#pragma unroll
    for (int ct = 0; ct < 4; ++ct)
#pragma unroll
      for (int r = 0; r < 4; ++r) acc1[ct][r] = 0.f;
#pragma unroll
    for (int ks = 0; ks < 2; ++ks) {
      v8bf a = *(v8bf*)&As[(w * 16 + l16) * LDA + ks * 32 + quad * 8];
#pragma unroll
      for (int ct = 0; ct < 4; ++ct) {
        v8bf bb = *(v8bf*)&B1s[(ct * 16 + l16) * LDA + ks * 32 + quad * 8];
        acc1[ct] = __builtin_amdgcn_mfma_f32_16x16x32_bf16(a, bb, acc1[ct], 0, 0, 0);
      }
    }
#pragma unroll
    for (int ct = 0; ct < 4; ++ct) {
      float bb = b1[c1 * 64 + ct * 16 + l16];
#pragma unroll
      for (int r = 0; r < 4; ++r) {
        float v = acc1[ct][r] + bb;
        v = 0.5f * v * (1.f + erff(v * 0.70710678118654752f));
        A2[(w * 16 + quad * 4 + r) * LDA + ct * 16 + l16] = (__bf16)v;
      }
    }
#pragma unroll
    for (int ks = 0; ks < 2; ++ks) {
      v8bf a = *(v8bf*)&A2[(w * 16 + l16) * LDA + ks * 32 + quad * 8];
#pragma unroll
      for (int ct = 0; ct < 4; ++ct) {
        v8bf bb = *(v8bf*)&B2s[(ct * 16 + l16) * LDA + ks * 32 + quad * 8];
        acc2[ct] = __builtin_amdgcn_mfma_f32_16x16x32_bf16(a, bb, acc2[ct], 0, 0, 0);
      }
    }
    __syncthreads();
  }

  // finalize H rows: v = acc2 + b2 + hr ; stash bf16 into A2 (A-layout)
#pragma unroll
  for (int ct = 0; ct < 4; ++ct) {
    int col = ct * 16 + l16;
    float bb = b2[col];
#pragma unroll
    for (int r = 0; r < 4; ++r) {
      int lrow = w * 16 + quad * 4 + r;
      size_t row = (size_t)t * NN + row0 + lrow;
      float v = acc2[ct][r] + bb + p.HN[row * 64 + col];
      if (p.mode == 1) p.H[row * 64 + col] = v;   // next agg needs Hin
      A2[lrow * LDA + col] = (__bf16)v;
    }
  }

  if (p.mode == 1) {
    // next-layer projections from final H
    int tq = 1 - t;
    ProjDesc pd[4];
    pd[0] = { p.Wq + (size_t)tq * 64 * 256, p.bq + tq * 256,
              (char*)p.Qb + (size_t)t * NN * 512, 256, 512, 1 };
    pd[1] = { p.Wk + (size_t)t * 64 * 256, p.bk + t * 256,
              p.KVb + (size_t)t * NN * 768, 256, 768, 2 };
    pd[2] = { p.Wv + (size_t)t * 64 * 256, p.bv + t * 256,
              p.KVb + (size_t)t * NN * 768 + 256, 256, 768, 1 };
    pd[3] = { p.Ws + (size_t)tq * 64 * 64, p.bs + tq * 64,
              (char*)(p.Rb + (size_t)t * NN * 64), 64, 256, 0 };
    project_from_lds(A2, B1s, pd, 4, row0, tid);
  } else {
    // out-proj
    ProjDesc pd[1];
    pd[0] = { p.Wout + (size_t)t * 64 * 64, p.bout + t * 64,
              (char*)(p.outbuf + (size_t)t * NN * 64), 64, 256, 0 };
    project_from_lds(A2, B1s, pd, 1, row0, tid);
  }
}

// ======================= edge aggregation + beta + LN (R8 structure, fp8 K) =======================
struct AggPack {
  const unsigned short *Q;   // [2*NN][256] bf16 (dst-type indexed)
  const char *KV;            // [2*NN] rows of 768 B (src-type indexed)
  const float *R;            // [2*NN][64]
  const float *Wb;
  const float *Hin;
  const float *lng, *lnb;
  float* outHR;
  const int *rowptr;
  const int *colsrc;         // byte offsets
};

__global__ __launch_bounds__(256) void agg_kernel(AggPack p) {
  const int et = blockIdx.y, d = 1 - et;
  int wid = __builtin_amdgcn_readfirstlane(threadIdx.x >> 6);
  int lane = threadIdx.x & 63;
  int node = blockIdx.x * 4 + wid;
  int c4 = lane & 15;
  int cb = ((lane >> 4) << 6) + (c4 << 2);   // channel index: head*64 + c4*4

  const int* rp = p.rowptr + et * (NN + 1);
  const int* cs = p.colsrc + et * EE;
  int start = rp[node], end = rp[node + 1];
  int len = end - start;
  int gnode = d * NN + node;

  uint2 qw = *(const uint2*)(p.Q + ((size_t)gnode << 8) + cb);
  float q0 = blo(qw.x) * 0.125f, q1 = bhi(qw.x) * 0.125f;
  float q2 = blo(qw.y) * 0.125f, q3 = bhi(qw.y) * 0.125f;

  int b[5];
#pragma unroll
  for (int i = 0; i <= 4; ++i) b[i] = start + ((len * i) >> 2);
  float dsum[4] = {0.f, 0.f, 0.f, 0.f};
  float acc[4][4];
#pragma unroll
  for (int s4 = 0; s4 < 4; ++s4)
#pragma unroll
    for (int c = 0; c < 4; ++c) acc[s4][c] = 0.f;

  int maxn = (len + 3) >> 2;
  int last = end - 1;
  for (int it = 0; it < maxn; ++it) {
#pragma unroll
    for (int s4 = 0; s4 < 4; ++s4) {
      int j = b[s4] + it;
      bool act = j < b[s4 + 1];
      int jc = act ? j : last;
      int off = cs[jc];                      // KV row byte offset
      const char* rowp = p.KV + off;
      unsigned kw = *(const unsigned*)(rowp + cb);          // 4 fp8 K vals
      uint2 vw = *(const uint2*)(rowp + 256 + cb * 2);      // 4 bf16 V vals
      v2f kl = __builtin_amdgcn_cvt_pk_f32_fp8((int)kw, false);
      v2f kh = __builtin_amdgcn_cvt_pk_f32_fp8((int)kw, true);
      float pd = q0 * kl[0] + q1 * kl[1] + q2 * kh[0] + q3 * kh[1];
      pd += __shfl_xor(pd, 1);
      pd += __shfl_xor(pd, 2);
      pd += __shfl_xor(pd, 4);
      pd += __shfl_xor(pd, 8);
      float wgt = act ? __expf(pd) : 0.f;
      dsum[s4] += wgt;
      acc[s4][0] += wgt * blo(vw.x);
      acc[s4][1] += wgt * bhi(vw.x);
      acc[s4][2] += wgt * blo(vw.y);
      acc[s4][3] += wgt * bhi(vw.y);
    }
  }
  // exact stream merge
  float dn = (dsum[0] + dsum[1]) + (dsum[2] + dsum[3]);
  float ax = (acc[0][0] + acc[1][0]) + (acc[2][0] + acc[3][0]);
  float ay = (acc[0][1] + acc[1][1]) + (acc[2][1] + acc[3][1]);
  float az = (acc[0][2] + acc[1][2]) + (acc[2][2] + acc[3][2]);
  float aw = (acc[0][3] + acc[1][3]) + (acc[2][3] + acc[3][3]);

  float inv = (len > 0) ? (0.25f / dn) : 0.f;
  float ox = ax * inv, oy = ay * inv, oz = az * inv, ow = aw * inv;
  ox += __shfl_xor(ox, 16); ox += __shfl_xor(ox, 32);
  oy += __shfl_xor(oy, 16); oy += __shfl_xor(oy, 32);
  oz += __shfl_xor(oz, 16); oz += __shfl_xor(oz, 32);
  ow += __shfl_xor(ow, 16); ow += __shfl_xor(ow, 32);

  int cc = c4 << 2;
  float4 r = *(const float4*)(p.R + (size_t)gnode * 64 + cc);
  const float* wb = p.Wb + et * 192;
  float part = ox * wb[cc] + oy * wb[cc + 1] + oz * wb[cc + 2] + ow * wb[cc + 3]
             + r.x * wb[64 + cc] + r.y * wb[64 + cc + 1]
             + r.z * wb[64 + cc + 2] + r.w * wb[64 + cc + 3]
             + (ox - r.x) * wb[128 + cc] + (oy - r.y) * wb[128 + cc + 1]
             + (oz - r.z) * wb[128 + cc + 2] + (ow - r.w) * wb[128 + cc + 3];
  part += __shfl_xor(part, 1);
  part += __shfl_xor(part, 2);
  part += __shfl_xor(part, 4);
  part += __shfl_xor(part, 8);
  float beta = 1.f / (1.f + __expf(-part));

  float4 hv = *(const float4*)(p.Hin + (size_t)gnode * 64 + cc);
  float yx = hv.x + beta * r.x + (1.f - beta) * ox;
  float yy = hv.y + beta * r.y + (1.f - beta) * oy;
  float yz = hv.z + beta * r.z + (1.f - beta) * oz;
  float yw = hv.w + beta * r.w + (1.f - beta) * ow;
  float sa = yx + yy + yz + yw;
  float sb = yx * yx + yy * yy + yz * yz + yw * yw;
  sa += __shfl_xor(sa, 1); sb += __shfl_xor(sb, 1);
  sa += __shfl_xor(sa, 2); sb += __shfl_xor(sb, 2);
  sa += __shfl_xor(sa, 4); sb += __shfl_xor(sb, 4);
  sa += __shfl_xor(sa, 8); sb += __shfl_xor(sb, 8);
  float mu = sa * (1.f / 64.f);
  float var = sb * (1.f / 64.f) - mu * mu;
  float rs = rsqrtf(var + 1e-5f);
  if (lane < 16) {
    const float* lng = p.lng + d * 64;
    const float* lnb = p.lnb + d * 64;
    float4 gg = *(const float4*)(lng + cc);
    float4 bb = *(const float4*)(lnb + cc);
    float4 res;
    res.x = (yx - mu) * rs * gg.x + bb.x;
    res.y = (yy - mu) * rs * gg.y + bb.y;
    res.z = (yz - mu) * rs * gg.z + bb.z;
    res.w = (yw - mu) * rs * gg.w + bb.w;
    *(float4*)(p.outHR + (size_t)gnode * 64 + cc) = res;
  }
}

// ======================= host =======================
extern "C" void kernel_launch(void* const* d_in, const int* in_sizes, int n_in,
                              void* d_out, int out_size, void* d_ws, size_t ws_size,
                              hipStream_t stream) {
  const float* x        = (const float*)d_in[0];
  const int*   ei       = (const int*)d_in[1];
  const float* W_in     = (const float*)d_in[2];
  const float* b_in     = (const float*)d_in[3];
  const float* type_emb = (const float*)d_in[4];
  const float* pos      = (const float*)d_in[5];
  const float* Wq       = (const float*)d_in[6];
  const float* bq       = (const float*)d_in[7];
  const float* Wk       = (const float*)d_in[8];
  const float* bk       = (const float*)d_in[9];
  const float* Wv       = (const float*)d_in[10];
  const float* bv       = (const float*)d_in[11];
  const float* Wskip    = (const float*)d_in[12];
  const float* bskip    = (const float*)d_in[13];
  const float* Wbeta    = (const float*)d_in[14];
  const float* ln_g     = (const float*)d_in[15];
  const float* ln_b     = (const float*)d_in[16];
  const float* ff_W1    = (const float*)d_in[17];
  const float* ff_b1    = (const float*)d_in[18];
  const float* ff_W2    = (const float*)d_in[19];
  const float* ff_b2    = (const float*)d_in[20];
  const float* W_out    = (const float*)d_in[21];
  const float* b_out    = (const float*)d_in[22];
  float* out = (float*)d_out;

  int*   wsi = (int*)d_ws;
  float* wsf = (float*)d_ws;
  int* cnt    = wsi + OFF_CNT;
  int* fill   = wsi + OFF_FILL;
  int* rowptr = wsi + OFF_ROWPTR;
  int* colsrc = wsi + OFF_COLSRC;
  float* H  = wsf + OFF_H;
  float* HN = wsf + OFF_HN;
  unsigned short* Qb = (unsigned short*)(wsf + OFF_Q);
  char* KVb = (char*)(wsf + OFF_KV);
  float* Rb = wsf + OFF_R;

  // ---- CSR build ----
  hipMemsetAsync(cnt, 0, 2 * NN * sizeof(int), stream);
  count_kernel<<<dim3(2 * EE / 256), dim3(256), 0, stream>>>(ei, cnt);
  scan_kernel<<<dim3(2), dim3(1024), 0, stream>>>(cnt, rowptr, fill);
  scatter_kernel<<<dim3(2 * EE / 256), dim3(256), 0, stream>>>(ei, fill, colsrc);

  // ---- fused input projection + layer-0 qkv/skip ----
  {
    InQkvPack ip;
    ip.x = x; ip.Win = W_in; ip.bin = b_in; ip.temb = type_emb; ip.pos = pos;
    ip.Wq = Wq; ip.bq = bq; ip.Wk = Wk; ip.bk = bk;
    ip.Wv = Wv; ip.bv = bv; ip.Ws = Wskip; ip.bs = bskip;
    ip.H = H; ip.Qb = Qb; ip.KVb = KVb; ip.Rb = Rb;
    in_qkv<<<dim3(NN / 64, 2), dim3(256), 0, stream>>>(ip);
  }

  for (int l = 0; l < 2; ++l) {
    AggPack ap;
    ap.Q = Qb; ap.KV = KVb; ap.R = Rb;
    ap.Wb = Wbeta + l * 2 * 192;
    ap.Hin = H;
    ap.lng = ln_g + l * 128;
    ap.lnb = ln_b + l * 128;
    ap.outHR = HN;
    ap.rowptr = rowptr;
    ap.colsrc = colsrc;
    agg_kernel<<<dim3(NN / 4, 2), dim3(256), 0, stream>>>(ap);

    FFPack fp;
    fp.HN = HN;
    fp.W1 = ff_W1 + (size_t)l * 2 * 64 * 256;
    fp.b1 = ff_b1 + l * 2 * 256;
    fp.W2 = ff_W2 + (size_t)l * 2 * 256 * 64;
    fp.b2 = ff_b2 + l * 2 * 64;
    fp.H  = H;
    if (l == 0) {
      fp.mode = 1;   // emit layer-1 qkv/skip
      fp.Wq = Wq + (size_t)2 * 64 * 256; fp.bq = bq + 2 * 256;
      fp.Wk = Wk + (size_t)2 * 64 * 256; fp.bk = bk + 2 * 256;
      fp.Wv = Wv + (size_t)2 * 64 * 256; fp.bv = bv + 2 * 256;
      fp.Ws = Wskip + (size_t)2 * 64 * 64; fp.bs = bskip + 2 * 64;
      fp.Qb = Qb; fp.KVb = KVb; fp.Rb = Rb;
      fp.Wout = nullptr; fp.bout = nullptr; fp.outbuf = nullptr;
    } else {
      fp.mode = 2;   // out-proj
      fp.Wq = fp.Wk = fp.Wv = fp.Ws = nullptr;
      fp.bq = fp.bk = fp.bv = fp.bs = nullptr;
      fp.Qb = nullptr; fp.KVb = nullptr; fp.Rb = nullptr;
      fp.Wout = W_out; fp.bout = b_out; fp.outbuf = out;
    }
    ff_fused<<<dim3(NN / 64, 2), dim3(256), 0, stream>>>(fp);
  }
}

// Round 12
// 366.494 us; speedup vs baseline: 1.1694x; 1.1694x over previous
//
#include <hip/hip_runtime.h>
#include <math.h>

#define NN 16384
#define EE 262144

typedef __bf16 v8bf __attribute__((ext_vector_type(8)));
typedef __bf16 v4bf __attribute__((ext_vector_type(4)));
typedef float  v4f  __attribute__((ext_vector_type(4)));
typedef float  v2f  __attribute__((ext_vector_type(2)));

// ---- workspace layout (units of 4-byte elements) ----
#define OFF_CNT     0                         // 2*NN ints
#define OFF_FILL    (2*NN)                    // 2*NN ints
#define OFF_ROWPTR  (4*NN)                    // 2*(NN+1) ints
#define OFF_COLSRC  98816                     // 2*EE ints (byte offsets)
#define OFF_H       623104                    // 2*NN*64 f32
#define OFF_HN      (OFF_H  + 2*NN*64)        // 2*NN*64 f32
#define OFF_Q       (OFF_HN + 2*NN*64)        // 2*NN*256 bf16 (512B rows)
#define OFF_KV      (OFF_Q  + 2*NN*128)       // 2*NN rows of 512 B (K fp8 256B | V fp8 256B)
#define OFF_R       (OFF_KV + 2*NN*128)       // 2*NN*64 f32

__device__ __forceinline__ float blo(unsigned u) { return __uint_as_float(u << 16); }
__device__ __forceinline__ float bhi(unsigned u) { return __uint_as_float(u & 0xffff0000u); }
__device__ __forceinline__ unsigned short f2b(float f) {
  __bf16 h = (__bf16)f;
  return *(unsigned short*)&h;
}

// ======================= CSR build =======================
__global__ void count_kernel(const int* __restrict__ ei, int* __restrict__ cnt) {
  int idx = blockIdx.x * 256 + threadIdx.x;
  if (idx >= 2 * EE) return;
  int et = idx >> 18;
  int j  = idx & (EE - 1);
  int dst = ei[et * 2 * EE + EE + j];
  atomicAdd(&cnt[et * NN + dst], 1);
}

__global__ __launch_bounds__(1024) void scan_kernel(const int* __restrict__ cnt,
                                                    int* __restrict__ rowptr,
                                                    int* __restrict__ fill) {
  int et = blockIdx.x;
  const int* c = cnt + et * NN;
  __shared__ int sums[1024];
  int tid = threadIdx.x;
  int base = tid * 16;
  int loc[16];
  int s = 0;
#pragma unroll
  for (int i = 0; i < 16; ++i) { loc[i] = s; s += c[base + i]; }
  sums[tid] = s;
  __syncthreads();
  for (int off = 1; off < 1024; off <<= 1) {
    int v = 0;
    if (tid >= off) v = sums[tid - off];
    __syncthreads();
    if (tid >= off) sums[tid] += v;
    __syncthreads();
  }
  int ebase = (tid == 0) ? 0 : sums[tid - 1];
  int* rp = rowptr + et * (NN + 1);
  int* fl = fill + et * NN;
#pragma unroll
  for (int i = 0; i < 16; ++i) {
    rp[base + i] = ebase + loc[i];
    fl[base + i] = ebase + loc[i];
  }
  if (tid == 1023) rp[NN] = sums[1023];
}

// colsrc holds BYTE offset of the src node's KV row: (et*NN + src) * 512
__global__ void scatter_kernel(const int* __restrict__ ei, int* __restrict__ fill,
                               int* __restrict__ colsrc) {
  int idx = blockIdx.x * 256 + threadIdx.x;
  if (idx >= 2 * EE) return;
  int et = idx >> 18;
  int j  = idx & (EE - 1);
  int src = ei[et * 2 * EE + j];
  int dst = ei[et * 2 * EE + EE + j];
  int pos = atomicAdd(&fill[et * NN + dst], 1);
  colsrc[et * EE + pos] = (et * NN + src) << 9;
}

// ======================= bf16 MFMA tiled GEMM (A staged once) =======================
// K=64 fixed. otype: 0=f32, 1=bf16, 2=fp8 e4m3. Cld = C row stride in BYTES.
struct GemmDesc {
  const float *A, *B, *bias, *bias2, *add;
  char* C;
  int Ncols, Cld, ntiles, gelu, otype;
};
struct GemmPack { GemmDesc d[8]; int nd; };

#define LDA 72   // padded bf16 row stride

__global__ __launch_bounds__(256) void gemm_mfma(GemmPack p) {
  GemmDesc g = p.d[blockIdx.y];
  const int row0 = blockIdx.x * 128;
  const int tid = threadIdx.x;
  const int w = tid >> 6, lane = tid & 63;
  const int l16 = lane & 15, quad = lane >> 4;

  __shared__ __bf16 As[128 * LDA];
  __shared__ __bf16 Bs[64 * LDA];

  // stage A rows once (K=64)
#pragma unroll
  for (int it = 0; it < 8; ++it) {
    int fi = it * 256 + tid;
    int grow = fi >> 4;
    int kq = (fi & 15) << 2;
    float4 a = *(const float4*)(g.A + (size_t)(row0 + grow) * 64 + kq);
    v4bf c = { (__bf16)a.x, (__bf16)a.y, (__bf16)a.z, (__bf16)a.w };
    *(v4bf*)&As[grow * LDA + kq] = c;
  }

  for (int ct0 = 0; ct0 < g.ntiles; ++ct0) {
    const int col0 = ct0 * 64;
    __syncthreads();   // A ready (iter 0) / prior MFMA done reading Bs
#pragma unroll
    for (int it = 0; it < 4; ++it) {
      int fi = it * 256 + tid;
      int kk = fi >> 4;
      int nq = (fi & 15) << 2;
      float4 b = *(const float4*)(g.B + (size_t)kk * g.Ncols + col0 + nq);
      Bs[(nq + 0) * LDA + kk] = (__bf16)b.x;
      Bs[(nq + 1) * LDA + kk] = (__bf16)b.y;
      Bs[(nq + 2) * LDA + kk] = (__bf16)b.z;
      Bs[(nq + 3) * LDA + kk] = (__bf16)b.w;
    }
    __syncthreads();

    v4f acc[2][4];
#pragma unroll
    for (int rt = 0; rt < 2; ++rt)
#pragma unroll
      for (int ct = 0; ct < 4; ++ct)
#pragma unroll
        for (int r = 0; r < 4; ++r) acc[rt][ct][r] = 0.f;

#pragma unroll
    for (int ks = 0; ks < 2; ++ks) {
      v8bf a0 = *(v8bf*)&As[(w * 32 + l16) * LDA + ks * 32 + quad * 8];
      v8bf a1 = *(v8bf*)&As[(w * 32 + 16 + l16) * LDA + ks * 32 + quad * 8];
#pragma unroll
      for (int ct = 0; ct < 4; ++ct) {
        v8bf bb = *(v8bf*)&Bs[(ct * 16 + l16) * LDA + ks * 32 + quad * 8];
        acc[0][ct] = __builtin_amdgcn_mfma_f32_16x16x32_bf16(a0, bb, acc[0][ct], 0, 0, 0);
        acc[1][ct] = __builtin_amdgcn_mfma_f32_16x16x32_bf16(a1, bb, acc[1][ct], 0, 0, 0);
      }
    }

    float bias_c[4];
#pragma unroll
    for (int ct = 0; ct < 4; ++ct) {
      int col = col0 + ct * 16 + l16;
      float b = g.bias ? g.bias[col] : 0.f;
      if (g.bias2) b += g.bias2[col];
      bias_c[ct] = b;
    }
#pragma unroll
    for (int rt = 0; rt < 2; ++rt)
#pragma unroll
      for (int r = 0; r < 4; ++r) {
        size_t row = row0 + w * 32 + rt * 16 + quad * 4 + r;
        char* cp = g.C + row * (size_t)g.Cld;
#pragma unroll
        for (int ct = 0; ct < 4; ++ct) {
          int col = col0 + ct * 16 + l16;
          float v = acc[rt][ct][r] + bias_c[ct];
          if (g.add) v += g.add[row * g.Ncols + col];
          if (g.gelu) v = 0.5f * v * (1.f + erff(v * 0.70710678118654752f));
          if (g.otype == 0)      *(float*)(cp + col * 4) = v;
          else if (g.otype == 1) *(unsigned short*)(cp + col * 2) = f2b(v);
          else {
            unsigned pk = __builtin_amdgcn_cvt_pk_fp8_f32(v, v, 0, false);
            *(unsigned char*)(cp + col) = (unsigned char)(pk & 0xff);
          }
        }
      }
  }
}

// ======================= fused FF (64 rows/block) + optional fused out-proj =======================
struct FFPack {
  const float *HN, *W1, *b1, *W2, *b2;
  float* H;
  const float *Wout, *bout;   // per-type [64][64], [64]
  float* outbuf;              // if non-null: write out = H@Wout+bout, skip H store
};

__global__ __launch_bounds__(256) void ff_fused(FFPack p) {
  const int t = blockIdx.y;
  const int row0 = blockIdx.x * 64;
  const int tid = threadIdx.x;
  const int w = tid >> 6, lane = tid & 63;
  const int l16 = lane & 15, quad = lane >> 4;

  const float* A  = p.HN + ((size_t)t * NN) * 64;
  const float* W1 = p.W1 + (size_t)t * 64 * 256;
  const float* b1 = p.b1 + t * 256;
  const float* W2 = p.W2 + (size_t)t * 256 * 64;
  const float* b2 = p.b2 + t * 64;

  __shared__ __bf16 As[64 * LDA];
  __shared__ __bf16 A2[64 * LDA];
  __shared__ __bf16 B1s[64 * LDA];
  __shared__ __bf16 B2s[64 * LDA];

#pragma unroll
  for (int it = 0; it < 4; ++it) {
    int fi = it * 256 + tid;
    int grow = fi >> 4;
    int kq = (fi & 15) << 2;
    float4 a = *(const float4*)(A + (size_t)(row0 + grow) * 64 + kq);
    v4bf c = { (__bf16)a.x, (__bf16)a.y, (__bf16)a.z, (__bf16)a.w };
    *(v4bf*)&As[grow * LDA + kq] = c;
  }

  v4f acc2[4];
#pragma unroll
  for (int ct = 0; ct < 4; ++ct)
#pragma unroll
    for (int r = 0; r < 4; ++r) acc2[ct][r] = 0.f;

  for (int c1 = 0; c1 < 4; ++c1) {
#pragma unroll
    for (int it = 0; it < 4; ++it) {
      int fi = it * 256 + tid;
      int kk = fi >> 4;
      int nq = (fi & 15) << 2;
      float4 b = *(const float4*)(W1 + (size_t)kk * 256 + c1 * 64 + nq);
      B1s[(nq + 0) * LDA + kk] = (__bf16)b.x;
      B1s[(nq + 1) * LDA + kk] = (__bf16)b.y;
      B1s[(nq + 2) * LDA + kk] = (__bf16)b.z;
      B1s[(nq + 3) * LDA + kk] = (__bf16)b.w;
      float4 b2v = *(const float4*)(W2 + (size_t)(c1 * 64 + kk) * 64 + nq);
      B2s[(nq + 0) * LDA + kk] = (__bf16)b2v.x;
      B2s[(nq + 1) * LDA + kk] = (__bf16)b2v.y;
      B2s[(nq + 2) * LDA + kk] = (__bf16)b2v.z;
      B2s[(nq + 3) * LDA + kk] = (__bf16)b2v.w;
    }
    __syncthreads();

    v4f acc1[4];
#pragma unroll
    for (int ct = 0; ct < 4; ++ct)
#pragma unroll
      for (int r = 0; r < 4; ++r) acc1[ct][r] = 0.f;
#pragma unroll
    for (int ks = 0; ks < 2; ++ks) {
      v8bf a = *(v8bf*)&As[(w * 16 + l16) * LDA + ks * 32 + quad * 8];
#pragma unroll
      for (int ct = 0; ct < 4; ++ct) {
        v8bf bb = *(v8bf*)&B1s[(ct * 16 + l16) * LDA + ks * 32 + quad * 8];
        acc1[ct] = __builtin_amdgcn_mfma_f32_16x16x32_bf16(a, bb, acc1[ct], 0, 0, 0);
      }
    }
#pragma unroll
    for (int ct = 0; ct < 4; ++ct) {
      float bb = b1[c1 * 64 + ct * 16 + l16];
#pragma unroll
      for (int r = 0; r < 4; ++r) {
        float v = acc1[ct][r] + bb;
        v = 0.5f * v * (1.f + erff(v * 0.70710678118654752f));
        A2[(w * 16 + quad * 4 + r) * LDA + ct * 16 + l16] = (__bf16)v;
      }
    }
#pragma unroll
    for (int ks = 0; ks < 2; ++ks) {
      v8bf a = *(v8bf*)&A2[(w * 16 + l16) * LDA + ks * 32 + quad * 8];
#pragma unroll
      for (int ct = 0; ct < 4; ++ct) {
        v8bf bb = *(v8bf*)&B2s[(ct * 16 + l16) * LDA + ks * 32 + quad * 8];
        acc2[ct] = __builtin_amdgcn_mfma_f32_16x16x32_bf16(a, bb, acc2[ct], 0, 0, 0);
      }
    }
    __syncthreads();
  }

  if (!p.outbuf) {
    // standard epilogue: H = hr + acc2 + b2
#pragma unroll
    for (int ct = 0; ct < 4; ++ct) {
      int col = ct * 16 + l16;
      float bb = b2[col];
#pragma unroll
      for (int r = 0; r < 4; ++r) {
        size_t row = (size_t)t * NN + row0 + w * 16 + quad * 4 + r;
        float v = acc2[ct][r] + bb + p.HN[row * 64 + col];
        p.H[row * 64 + col] = v;
      }
    }
    return;
  }

  // ---- fused output projection (last layer): out = (hr+ff) @ Wout + bout ----
#pragma unroll
  for (int ct = 0; ct < 4; ++ct) {
    int col = ct * 16 + l16;
    float bb = b2[col];
#pragma unroll
    for (int r = 0; r < 4; ++r) {
      int lrow = w * 16 + quad * 4 + r;
      size_t row = (size_t)t * NN + row0 + lrow;
      float v = acc2[ct][r] + bb + p.HN[row * 64 + col];
      A2[lrow * LDA + col] = (__bf16)v;
    }
  }
  {
    const float* Wo = p.Wout + (size_t)t * 64 * 64;
#pragma unroll
    for (int it = 0; it < 4; ++it) {
      int fi = it * 256 + tid;
      int kk = fi >> 4;
      int nq = (fi & 15) << 2;
      float4 b = *(const float4*)(Wo + (size_t)kk * 64 + nq);
      B1s[(nq + 0) * LDA + kk] = (__bf16)b.x;
      B1s[(nq + 1) * LDA + kk] = (__bf16)b.y;
      B1s[(nq + 2) * LDA + kk] = (__bf16)b.z;
      B1s[(nq + 3) * LDA + kk] = (__bf16)b.w;
    }
  }
  __syncthreads();

  v4f acc3[4];
#pragma unroll
  for (int ct = 0; ct < 4; ++ct)
#pragma unroll
    for (int r = 0; r < 4; ++r) acc3[ct][r] = 0.f;
#pragma unroll
  for (int ks = 0; ks < 2; ++ks) {
    v8bf a = *(v8bf*)&A2[(w * 16 + l16) * LDA + ks * 32 + quad * 8];
#pragma unroll
    for (int ct = 0; ct < 4; ++ct) {
      v8bf bb = *(v8bf*)&B1s[(ct * 16 + l16) * LDA + ks * 32 + quad * 8];
      acc3[ct] = __builtin_amdgcn_mfma_f32_16x16x32_bf16(a, bb, acc3[ct], 0, 0, 0);
    }
  }
  const float* bo = p.bout + t * 64;
#pragma unroll
  for (int ct = 0; ct < 4; ++ct) {
    int col = ct * 16 + l16;
    float bb = bo[col];
#pragma unroll
    for (int r = 0; r < 4; ++r) {
      size_t row = (size_t)t * NN + row0 + w * 16 + quad * 4 + r;
      p.outbuf[row * 64 + col] = acc3[ct][r] + bb;
    }
  }
}

// ======================= edge aggregation + beta + LN (fp8 K AND fp8 V) =======================
// grid.y = edge type; one wave / dst node; lane = head*16 + c4.
// KV row 512 B: K fp8 [0,256) | V fp8 [256,512). No-max softmax, 4 uniform streams.
struct AggPack {
  const unsigned short *Q;   // [2*NN][256] bf16 (dst-type indexed)
  const char *KV;            // [2*NN] rows of 512 B (src-type indexed)
  const float *R;            // [2*NN][64]
  const float *Wb;
  const float *Hin;
  const float *lng, *lnb;
  float* outHR;
  const int *rowptr;
  const int *colsrc;         // byte offsets
};

__global__ __launch_bounds__(256) void agg_kernel(AggPack p) {
  const int et = blockIdx.y, d = 1 - et;
  int wid = __builtin_amdgcn_readfirstlane(threadIdx.x >> 6);
  int lane = threadIdx.x & 63;
  int node = blockIdx.x * 4 + wid;
  int c4 = lane & 15;
  int cb = ((lane >> 4) << 6) + (c4 << 2);   // channel index: head*64 + c4*4

  const int* rp = p.rowptr + et * (NN + 1);
  const int* cs = p.colsrc + et * EE;
  int start = rp[node], end = rp[node + 1];
  int len = end - start;
  int gnode = d * NN + node;

  uint2 qw = *(const uint2*)(p.Q + ((size_t)gnode << 8) + cb);
  float q0 = blo(qw.x) * 0.125f, q1 = bhi(qw.x) * 0.125f;
  float q2 = blo(qw.y) * 0.125f, q3 = bhi(qw.y) * 0.125f;

  int b[5];
#pragma unroll
  for (int i = 0; i <= 4; ++i) b[i] = start + ((len * i) >> 2);
  float dsum[4] = {0.f, 0.f, 0.f, 0.f};
  float acc[4][4];
#pragma unroll
  for (int s4 = 0; s4 < 4; ++s4)
#pragma unroll
    for (int c = 0; c < 4; ++c) acc[s4][c] = 0.f;

  int maxn = (len + 3) >> 2;
  int last = end - 1;
  for (int it = 0; it < maxn; ++it) {
#pragma unroll
    for (int s4 = 0; s4 < 4; ++s4) {
      int j = b[s4] + it;
      bool act = j < b[s4 + 1];
      int jc = act ? j : last;
      int off = cs[jc];                      // KV row byte offset
      const char* rowp = p.KV + off;
      unsigned kw = *(const unsigned*)(rowp + cb);          // 4 fp8 K vals
      unsigned vw = *(const unsigned*)(rowp + 256 + cb);    // 4 fp8 V vals
      v2f kl = __builtin_amdgcn_cvt_pk_f32_fp8((int)kw, false);
      v2f kh = __builtin_amdgcn_cvt_pk_f32_fp8((int)kw, true);
      float pd = q0 * kl[0] + q1 * kl[1] + q2 * kh[0] + q3 * kh[1];
      pd += __shfl_xor(pd, 1);
      pd += __shfl_xor(pd, 2);
      pd += __shfl_xor(pd, 4);
      pd += __shfl_xor(pd, 8);
      float wgt = act ? __expf(pd) : 0.f;
      v2f vl = __builtin_amdgcn_cvt_pk_f32_fp8((int)vw, false);
      v2f vh = __builtin_amdgcn_cvt_pk_f32_fp8((int)vw, true);
      dsum[s4] += wgt;
      acc[s4][0] += wgt * vl[0];
      acc[s4][1] += wgt * vl[1];
      acc[s4][2] += wgt * vh[0];
      acc[s4][3] += wgt * vh[1];
    }
  }
  // exact stream merge
  float dn = (dsum[0] + dsum[1]) + (dsum[2] + dsum[3]);
  float ax = (acc[0][0] + acc[1][0]) + (acc[2][0] + acc[3][0]);
  float ay = (acc[0][1] + acc[1][1]) + (acc[2][1] + acc[3][1]);
  float az = (acc[0][2] + acc[1][2]) + (acc[2][2] + acc[3][2]);
  float aw = (acc[0][3] + acc[1][3]) + (acc[2][3] + acc[3][3]);

  float inv = (len > 0) ? (0.25f / dn) : 0.f;
  float ox = ax * inv, oy = ay * inv, oz = az * inv, ow = aw * inv;
  ox += __shfl_xor(ox, 16); ox += __shfl_xor(ox, 32);
  oy += __shfl_xor(oy, 16); oy += __shfl_xor(oy, 32);
  oz += __shfl_xor(oz, 16); oz += __shfl_xor(oz, 32);
  ow += __shfl_xor(ow, 16); ow += __shfl_xor(ow, 32);

  int cc = c4 << 2;
  float4 r = *(const float4*)(p.R + (size_t)gnode * 64 + cc);
  const float* wb = p.Wb + et * 192;
  float part = ox * wb[cc] + oy * wb[cc + 1] + oz * wb[cc + 2] + ow * wb[cc + 3]
             + r.x * wb[64 + cc] + r.y * wb[64 + cc + 1]
             + r.z * wb[64 + cc + 2] + r.w * wb[64 + cc + 3]
             + (ox - r.x) * wb[128 + cc] + (oy - r.y) * wb[128 + cc + 1]
             + (oz - r.z) * wb[128 + cc + 2] + (ow - r.w) * wb[128 + cc + 3];
  part += __shfl_xor(part, 1);
  part += __shfl_xor(part, 2);
  part += __shfl_xor(part, 4);
  part += __shfl_xor(part, 8);
  float beta = 1.f / (1.f + __expf(-part));

  float4 hv = *(const float4*)(p.Hin + (size_t)gnode * 64 + cc);
  float yx = hv.x + beta * r.x + (1.f - beta) * ox;
  float yy = hv.y + beta * r.y + (1.f - beta) * oy;
  float yz = hv.z + beta * r.z + (1.f - beta) * oz;
  float yw = hv.w + beta * r.w + (1.f - beta) * ow;
  float sa = yx + yy + yz + yw;
  float sb = yx * yx + yy * yy + yz * yz + yw * yw;
  sa += __shfl_xor(sa, 1); sb += __shfl_xor(sb, 1);
  sa += __shfl_xor(sa, 2); sb += __shfl_xor(sb, 2);
  sa += __shfl_xor(sa, 4); sb += __shfl_xor(sb, 4);
  sa += __shfl_xor(sa, 8); sb += __shfl_xor(sb, 8);
  float mu = sa * (1.f / 64.f);
  float var = sb * (1.f / 64.f) - mu * mu;
  float rs = rsqrtf(var + 1e-5f);
  if (lane < 16) {
    const float* lng = p.lng + d * 64;
    const float* lnb = p.lnb + d * 64;
    float4 gg = *(const float4*)(lng + cc);
    float4 bb = *(const float4*)(lnb + cc);
    float4 res;
    res.x = (yx - mu) * rs * gg.x + bb.x;
    res.y = (yy - mu) * rs * gg.y + bb.y;
    res.z = (yz - mu) * rs * gg.z + bb.z;
    res.w = (yw - mu) * rs * gg.w + bb.w;
    *(float4*)(p.outHR + (size_t)gnode * 64 + cc) = res;
  }
}

// ======================= host =======================
static void add_desc(GemmPack& p, const float* A, const float* B,
                     const float* bias, const float* bias2, const float* add,
                     void* C, int Nc, int Cld, int gelu, int otype) {
  GemmDesc& g = p.d[p.nd++];
  g.A = A; g.B = B; g.bias = bias; g.bias2 = bias2; g.add = add; g.C = (char*)C;
  g.Ncols = Nc; g.Cld = Cld; g.ntiles = Nc / 64;
  g.gelu = gelu; g.otype = otype;
}

extern "C" void kernel_launch(void* const* d_in, const int* in_sizes, int n_in,
                              void* d_out, int out_size, void* d_ws, size_t ws_size,
                              hipStream_t stream) {
  const float* x        = (const float*)d_in[0];
  const int*   ei       = (const int*)d_in[1];
  const float* W_in     = (const float*)d_in[2];
  const float* b_in     = (const float*)d_in[3];
  const float* type_emb = (const float*)d_in[4];
  const float* pos      = (const float*)d_in[5];
  const float* Wq       = (const float*)d_in[6];
  const float* bq       = (const float*)d_in[7];
  const float* Wk       = (const float*)d_in[8];
  const float* bk       = (const float*)d_in[9];
  const float* Wv       = (const float*)d_in[10];
  const float* bv       = (const float*)d_in[11];
  const float* Wskip    = (const float*)d_in[12];
  const float* bskip    = (const float*)d_in[13];
  const float* Wbeta    = (const float*)d_in[14];
  const float* ln_g     = (const float*)d_in[15];
  const float* ln_b     = (const float*)d_in[16];
  const float* ff_W1    = (const float*)d_in[17];
  const float* ff_b1    = (const float*)d_in[18];
  const float* ff_W2    = (const float*)d_in[19];
  const float* ff_b2    = (const float*)d_in[20];
  const float* W_out    = (const float*)d_in[21];
  const float* b_out    = (const float*)d_in[22];
  float* out = (float*)d_out;

  int*   wsi = (int*)d_ws;
  float* wsf = (float*)d_ws;
  int* cnt    = wsi + OFF_CNT;
  int* fill   = wsi + OFF_FILL;
  int* rowptr = wsi + OFF_ROWPTR;
  int* colsrc = wsi + OFF_COLSRC;
  float* H  = wsf + OFF_H;
  float* HN = wsf + OFF_HN;
  unsigned short* Qb = (unsigned short*)(wsf + OFF_Q);
  char* KVb = (char*)(wsf + OFF_KV);
  float* Rb = wsf + OFF_R;

  // ---- CSR build ----
  hipMemsetAsync(cnt, 0, 2 * NN * sizeof(int), stream);
  count_kernel<<<dim3(2 * EE / 256), dim3(256), 0, stream>>>(ei, cnt);
  scan_kernel<<<dim3(2), dim3(1024), 0, stream>>>(cnt, rowptr, fill);
  scatter_kernel<<<dim3(2 * EE / 256), dim3(256), 0, stream>>>(ei, fill, colsrc);

  // ---- input projection ----
  {
    GemmPack p{};
    for (int t = 0; t < 2; ++t)
      add_desc(p, x + (size_t)t * NN * 64, W_in + t * 64 * 64,
               b_in + t * 64, type_emb + t * 64, pos + (size_t)t * NN * 64,
               H + (size_t)t * NN * 64, 64, 256, 0, 0);
    gemm_mfma<<<dim3(128, p.nd), dim3(256), 0, stream>>>(p);
  }

  for (int l = 0; l < 2; ++l) {
    // one batched GEMM for both edge types: q,k,v,skip x 2
    {
      GemmPack p{};
      for (int et = 0; et < 2; ++et) {
        int s = et, d = 1 - et;
        int we = l * 2 + et;
        const float* hs = H + (size_t)s * NN * 64;
        const float* hd = H + (size_t)d * NN * 64;
        add_desc(p, hd, Wq + (size_t)we * 64 * 256, bq + we * 256,
                 nullptr, nullptr, (char*)Qb + (size_t)d * NN * 512, 256, 512, 0, 1);
        add_desc(p, hs, Wk + (size_t)we * 64 * 256, bk + we * 256,
                 nullptr, nullptr, KVb + (size_t)s * NN * 512, 256, 512, 0, 2);
        add_desc(p, hs, Wv + (size_t)we * 64 * 256, bv + we * 256,
                 nullptr, nullptr, KVb + (size_t)s * NN * 512 + 256, 256, 512, 0, 2);
        add_desc(p, hd, Wskip + (size_t)we * 64 * 64, bskip + we * 64,
                 nullptr, nullptr, Rb + (size_t)d * NN * 64, 64, 256, 0, 0);
      }
      gemm_mfma<<<dim3(128, p.nd), dim3(256), 0, stream>>>(p);
    }

    AggPack ap;
    ap.Q = Qb; ap.KV = KVb; ap.R = Rb;
    ap.Wb = Wbeta + l * 2 * 192;
    ap.Hin = H;
    ap.lng = ln_g + l * 128;
    ap.lnb = ln_b + l * 128;
    ap.outHR = HN;
    ap.rowptr = rowptr;
    ap.colsrc = colsrc;
    agg_kernel<<<dim3(NN / 4, 2), dim3(256), 0, stream>>>(ap);

    FFPack fp;
    fp.HN = HN;
    fp.W1 = ff_W1 + (size_t)l * 2 * 64 * 256;
    fp.b1 = ff_b1 + l * 2 * 256;
    fp.W2 = ff_W2 + (size_t)l * 2 * 256 * 64;
    fp.b2 = ff_b2 + l * 2 * 64;
    fp.H  = H;
    fp.Wout = W_out;
    fp.bout = b_out;
    fp.outbuf = (l == 1) ? out : nullptr;   // fuse output projection into last FF
    ff_fused<<<dim3(NN / 64, 2), dim3(256), 0, stream>>>(fp);
  }
}